// Round 5
// baseline (248.091 us; speedup 1.0000x reference)
//
#include <hip/hip_runtime.h>
#include <stdint.h>

#define NB 64
#define SEQL 512
#define L 510
#define T 9
#define H 768
#define EMS 12           // padded emission row stride (floats)
#define LN2 0.6931471805599453f

__device__ __forceinline__ float rl(float v, int l) {
  return __uint_as_float(__builtin_amdgcn_readlane(__float_as_uint(v), l));
}

// ---------------- K_A: per-window emissions (LDS) + den scan + viterbi scan --
// grid 1024 = (batch b, window s). Phase A: GEMV for this window's rows into
// LDS + global em. Phase B: wave0 = den transfer matrix, wave1 = viterbi
// max-plus transfer matrix, both reading emissions from LDS.
__global__ __launch_bounds__(256) void ka_kernel(
    const float* __restrict__ hidden, const float* __restrict__ weight,
    const float* __restrict__ bias, const float* __restrict__ trans,
    float* __restrict__ em, float* __restrict__ PdLn, float* __restrict__ Mv,
    float* __restrict__ out) {
  __shared__ float4 wl[1728];       // 9x768 floats = 27648 B
  __shared__ float s_em[33 * 12];   // up to 33 rows
  __shared__ float s_ee[33 * 12];
  const int tid = threadIdx.x;
  const int w = blockIdx.x;         // window id = b*16 + s
  const int b = w >> 4, s = w & 15;
  const int nt = (s == 15) ? 29 : 32;
  const int l0 = 32 * s + 1;
  const int off0 = (s == 0) ? 1 : 0;   // s==0 also computes row l=0
  const int nrows = nt + off0;
  const int lstart = l0 - off0;

  const float4* w4 = (const float4*)weight;
  for (int k = tid; k < 1728; k += 256) wl[k] = w4[k];
  if (w == 0 && tid == 0) out[0] = 0.f;  // atomic target init (K_B runs after)
  __syncthreads();

  const int lane = tid & 63, wv = tid >> 6;
  float bs[9];
#pragma unroll
  for (int t = 0; t < 9; ++t) bs[t] = bias[t];

  // ---- phase A: emissions, one wave per row ----
  for (int r = wv; r < nrows; r += 4) {
    const float4* h4 = (const float4*)(hidden + ((size_t)(b * SEQL + lstart + r + 1)) * H);
    float4 h0 = h4[lane], h1 = h4[lane + 64], h2 = h4[lane + 128];
    float acc[9];
#pragma unroll
    for (int t = 0; t < 9; ++t) acc[t] = 0.f;
#pragma unroll
    for (int t = 0; t < 9; ++t) {
      float4 wa = wl[t * 192 + lane];
      float4 wb = wl[t * 192 + lane + 64];
      float4 wc = wl[t * 192 + lane + 128];
      acc[t] = fmaf(h0.x, wa.x, fmaf(h0.y, wa.y, fmaf(h0.z, wa.z, fmaf(h0.w, wa.w, acc[t]))));
      acc[t] = fmaf(h1.x, wb.x, fmaf(h1.y, wb.y, fmaf(h1.z, wb.z, fmaf(h1.w, wb.w, acc[t]))));
      acc[t] = fmaf(h2.x, wc.x, fmaf(h2.y, wc.y, fmaf(h2.z, wc.z, fmaf(h2.w, wc.w, acc[t]))));
    }
#pragma unroll
    for (int off = 32; off; off >>= 1) {
#pragma unroll
      for (int t = 0; t < 9; ++t) acc[t] += __shfl_xor(acc[t], off);
    }
    if (lane == 0) {
      float* eo = em + ((size_t)(b * L + lstart + r)) * EMS;
#pragma unroll
      for (int t = 0; t < 9; ++t) {
        float v = acc[t] + bs[t];
        s_em[r * 12 + t] = v;
        s_ee[r * 12 + t] = __expf(v);
        eo[t] = v;
      }
    }
  }
  __syncthreads();

  // ---- phase B ----
  if (tid < 64) {
    // ===== den: linear-domain transfer matrix with pow2 rescale =====
    const int i9 = lane < 9 ? lane : 8;
    float E[81];
#pragma unroll
    for (int k = 0; k < 81; ++k) E[k] = __expf(trans[k]);
    const float* ee0 = s_ee + off0 * 12;
    float R[9];
#pragma unroll
    for (int j = 0; j < 9; ++j) R[j] = E[i9 * 9 + j] * ee0[j];
    int iexp = 0;
    for (int t = 1; t < nt; ++t) {
      const float* e = ee0 + t * 12;
      float4 ea = *(const float4*)e;
      float4 eb = *(const float4*)(e + 4);
      float e8 = e[8];
      float Rn[9];
#pragma unroll
      for (int j = 0; j < 9; ++j) {
        float a = R[0] * E[0 * 9 + j];
#pragma unroll
        for (int k = 1; k < 9; ++k) a = fmaf(R[k], E[k * 9 + j], a);
        Rn[j] = a;
      }
      R[0] = Rn[0] * ea.x; R[1] = Rn[1] * ea.y; R[2] = Rn[2] * ea.z;
      R[3] = Rn[3] * ea.w; R[4] = Rn[4] * eb.x; R[5] = Rn[5] * eb.y;
      R[6] = Rn[6] * eb.z; R[7] = Rn[7] * eb.w; R[8] = Rn[8] * e8;
      if ((t & 3) == 0) {  // power-of-2 rescale
        float mx = R[0];
#pragma unroll
        for (int j = 1; j < 9; ++j) mx = fmaxf(mx, R[j]);
        int ex = (int)((__float_as_uint(mx) >> 23) & 0xff) - 127;
        iexp += ex;
        float sc = __uint_as_float((uint32_t)(127 - ex) << 23);
#pragma unroll
        for (int j = 0; j < 9; ++j) R[j] *= sc;
      }
    }
    if (lane < 9) {
      float ls = (float)iexp * LN2;
#pragma unroll
      for (int j = 0; j < 9; ++j)
        PdLn[(size_t)w * 81 + j * 9 + lane] = __logf(R[j]) + ls;
    }
  } else if (tid < 128) {
    // ===== viterbi: max-plus transfer matrix =====
    const int i9 = lane < 9 ? lane : 8;
    float t_[81];
#pragma unroll
    for (int k = 0; k < 81; ++k) t_[k] = trans[k];
    const float* e0 = s_em + off0 * 12;
    float V[9];
#pragma unroll
    for (int j = 0; j < 9; ++j) V[j] = t_[i9 * 9 + j] + e0[j];
    for (int t = 1; t < nt; ++t) {
      const float* e = e0 + t * 12;
      float4 ea = *(const float4*)e;
      float4 eb = *(const float4*)(e + 4);
      float e8 = e[8];
      float ex[9] = {ea.x, ea.y, ea.z, ea.w, eb.x, eb.y, eb.z, eb.w, e8};
      float Vn[9];
#pragma unroll
      for (int j = 0; j < 9; ++j) {
        float m = V[0] + t_[0 * 9 + j];
#pragma unroll
        for (int k = 1; k < 9; ++k) m = fmaxf(m, V[k] + t_[k * 9 + j]);
        Vn[j] = m + ex[j];
      }
#pragma unroll
      for (int j = 0; j < 9; ++j) V[j] = Vn[j];
    }
    if (lane < 9) {
#pragma unroll
      for (int j = 0; j < 9; ++j)
        Mv[(size_t)w * 81 + j * 9 + lane] = V[j];  // column-major [j][i]
    }
  }
}

// ---------------- K_B: per-batch compose + numerator + path re-run -----------
__global__ __launch_bounds__(256) void kb_kernel(
    const float* __restrict__ em, const int* __restrict__ labels,
    const float* __restrict__ PdLn, const float* __restrict__ Mv,
    const float* __restrict__ start_t, const float* __restrict__ end_t,
    const float* __restrict__ trans, float* __restrict__ out) {
  __shared__ float s_pd[1296];
  __shared__ float s_mv[1296];
  __shared__ float s_A[153];
  __shared__ float s_t[81];
  __shared__ float s_np[4];
  __shared__ int s_lab[L];
  __shared__ unsigned char s_ch[32];
  __shared__ uint32_t s_bp[32 * 16 * 2];  // [(q*16+s)*2+word]
  const int b = blockIdx.x;
  const int tid = threadIdx.x;
  for (int k = tid; k < 1296; k += 256) {
    s_pd[k] = PdLn[(size_t)b * 1296 + k];
    s_mv[k] = Mv[(size_t)b * 1296 + k];
  }
  for (int k = tid; k < 81; k += 256) s_t[k] = trans[k];
  for (int k = tid; k < L; k += 256) s_lab[k] = labels[b * SEQL + 1 + k];
  __syncthreads();

  // ---- numerator (mask all-true): 256 threads ----
  float part = 0.f;
  for (int l = tid; l < L; l += 256) {
    int tg = s_lab[l];
    float e = em[((size_t)(b * L + l)) * EMS + tg];
    if (l == 0) part += start_t[tg] + e;
    else part += s_t[s_lab[l - 1] * 9 + tg] + e;
    if (l == L - 1) part += end_t[tg];
  }
#pragma unroll
  for (int off = 32; off; off >>= 1) part += __shfl_xor(part, off);
  if ((tid & 63) == 0) s_np[tid >> 6] = part;
  __syncthreads();

  if (tid < 64) {
    const int lane = tid;
    const int jj = lane < 9 ? lane : 8;

    // ---- denominator: 16 LSE compose steps ----
    float D = start_t[jj] + em[(size_t)b * L * EMS + jj];
    for (int s = 0; s < 16; ++s) {
      const float* col = &s_pd[s * 81 + jj * 9];
      float v0 = rl(D, 0) + col[0], v1 = rl(D, 1) + col[1], v2 = rl(D, 2) + col[2];
      float v3 = rl(D, 3) + col[3], v4 = rl(D, 4) + col[4], v5 = rl(D, 5) + col[5];
      float v6 = rl(D, 6) + col[6], v7 = rl(D, 7) + col[7], v8 = rl(D, 8) + col[8];
      float mx = fmaxf(fmaxf(fmaxf(fmaxf(v0, v1), fmaxf(v2, v3)),
                             fmaxf(fmaxf(v4, v5), fmaxf(v6, v7))), v8);
      float sum = __expf(v0 - mx) + __expf(v1 - mx) + __expf(v2 - mx) +
                  __expf(v3 - mx) + __expf(v4 - mx) + __expf(v5 - mx) +
                  __expf(v6 - mx) + __expf(v7 - mx) + __expf(v8 - mx);
      D = mx + __logf(sum);
    }
    float fe = D + end_t[jj];
    float w0 = rl(fe, 0), w1 = rl(fe, 1), w2 = rl(fe, 2), w3 = rl(fe, 3);
    float w4 = rl(fe, 4), w5 = rl(fe, 5), w6 = rl(fe, 6), w7 = rl(fe, 7), w8 = rl(fe, 8);
    float mx = fmaxf(fmaxf(fmaxf(fmaxf(w0, w1), fmaxf(w2, w3)),
                           fmaxf(fmaxf(w4, w5), fmaxf(w6, w7))), w8);
    float den = mx + __logf(__expf(w0 - mx) + __expf(w1 - mx) + __expf(w2 - mx) +
                            __expf(w3 - mx) + __expf(w4 - mx) + __expf(w5 - mx) +
                            __expf(w6 - mx) + __expf(w7 - mx) + __expf(w8 - mx));
    if (lane == 0)
      atomicAdd(out, den - (s_np[0] + s_np[1] + s_np[2] + s_np[3]));

    // ---- viterbi boundary alphas (max-plus compose) ----
    float A = start_t[jj] + em[(size_t)b * L * EMS + jj];
    if (lane < 9) s_A[lane] = A;
    for (int s = 0; s < 16; ++s) {
      const float* col = &s_mv[s * 81 + jj * 9];
      float u0 = rl(A, 0) + col[0], u1 = rl(A, 1) + col[1], u2 = rl(A, 2) + col[2];
      float u3 = rl(A, 3) + col[3], u4 = rl(A, 4) + col[4], u5 = rl(A, 5) + col[5];
      float u6 = rl(A, 6) + col[6], u7 = rl(A, 7) + col[7], u8 = rl(A, 8) + col[8];
      A = fmaxf(fmaxf(fmaxf(fmaxf(u0, u1), fmaxf(u2, u3)),
                      fmaxf(fmaxf(u4, u5), fmaxf(u6, u7))), u8);
      if (lane < 9) s_A[(s + 1) * 9 + lane] = A;
    }
    float fv = A + end_t[jj];
    int j = 0;
    {
      float bv = rl(fv, 0);
#pragma unroll
      for (int i = 1; i < 9; ++i) { float v = rl(fv, i); if (v > bv) { bv = v; j = i; } }
    }
    // ---- chunk-level backward chase ----
    for (int s = 15; s >= 0; --s) {
      float val = s_A[s * 9 + jj] + s_mv[s * 81 + j * 9 + jj];
      int ii = 0;
      float bb = rl(val, 0);
#pragma unroll
      for (int i = 1; i < 9; ++i) { float v = rl(val, i); if (v > bb) { bb = v; ii = i; } }
      if (lane == 0) {
        s_ch[s * 2] = (unsigned char)ii;
        s_ch[s * 2 + 1] = (unsigned char)j;
      }
      j = ii;
    }
    if (lane == 0) out[1 + (size_t)b * L] = (float)j;  // tag at position 0
  }
  __syncthreads();

  // ---- path re-run: thread s = window s ----
  if (tid < 16) {
    const int s = tid;
    const int nt = (s == 15) ? 29 : 32;
    const int l0 = 32 * s + 1;
    const int i0 = s_ch[s * 2];
    const int jF = s_ch[s * 2 + 1];
    float t_[81];
#pragma unroll
    for (int k = 0; k < 81; ++k) t_[k] = trans[k];  // uniform -> scalar loads
    const float* ep = em + ((size_t)(b * L + l0)) * EMS;
    float a[9];
    {
      float4 ea = *(const float4*)(ep);
      float4 eb = *(const float4*)(ep + 4);
      float e8 = ep[8];
      float e[9] = {ea.x, ea.y, ea.z, ea.w, eb.x, eb.y, eb.z, eb.w, e8};
#pragma unroll
      for (int jx = 0; jx < 9; ++jx) a[jx] = t_[i0 * 9 + jx] + e[jx];
    }
    for (int q = 1; q < nt; ++q) {
      float4 na = *(const float4*)(ep + (size_t)q * EMS);
      float4 nb = *(const float4*)(ep + (size_t)q * EMS + 4);
      float n8 = ep[(size_t)q * EMS + 8];
      float e[9] = {na.x, na.y, na.z, na.w, nb.x, nb.y, nb.z, nb.w, n8};
      uint32_t pk0 = 0, pk1 = 0;
      float an[9];
#pragma unroll
      for (int jx = 0; jx < 9; ++jx) {
        float best = a[0] + t_[0 * 9 + jx];
        int bi = 0;
#pragma unroll
        for (int k = 1; k < 9; ++k) {
          float v = a[k] + t_[k * 9 + jx];
          if (v > best) { best = v; bi = k; }
        }
        an[jx] = best + e[jx];
        if (jx < 8) pk0 |= ((uint32_t)bi) << (4 * jx);
        else pk1 = (uint32_t)bi;
      }
      s_bp[(q * 16 + s) * 2] = pk0;
      s_bp[(q * 16 + s) * 2 + 1] = pk1;
#pragma unroll
      for (int jx = 0; jx < 9; ++jx) a[jx] = an[jx];
    }
    int cur = jF;
    float* orow = out + 1 + (size_t)b * L + l0;
    for (int q = nt - 1; q >= 1; --q) {
      orow[q] = (float)cur;
      uint32_t pk = s_bp[(q * 16 + s) * 2 + (cur >> 3)];
      cur = (int)((pk >> ((cur & 7) * 4)) & 15u);
    }
    orow[0] = (float)cur;
  }
}

extern "C" void kernel_launch(void* const* d_in, const int* in_sizes, int n_in,
                              void* d_out, int out_size, void* d_ws, size_t ws_size,
                              hipStream_t stream) {
  const float* hidden  = (const float*)d_in[0];
  const int*   labels  = (const int*)d_in[1];
  const float* weight  = (const float*)d_in[2];
  const float* bias    = (const float*)d_in[3];
  const float* start_t = (const float*)d_in[4];
  const float* end_t   = (const float*)d_in[5];
  const float* trans   = (const float*)d_in[6];
  float* out = (float*)d_out;

  float* em   = (float*)d_ws;                 // 64*510*12 = 391680 f
  float* PdLn = em + (size_t)NB * L * EMS;    // 1024*81 f
  float* Mv   = PdLn + (size_t)1024 * 81;     // 1024*81 f

  ka_kernel<<<1024, 256, 0, stream>>>(hidden, weight, bias, trans, em, PdLn, Mv, out);
  kb_kernel<<<NB, 256, 0, stream>>>(em, labels, PdLn, Mv, start_t, end_t, trans, out);
}

// Round 6
// 233.572 us; speedup vs baseline: 1.0622x; 1.0622x over previous
//
#include <hip/hip_runtime.h>
#include <stdint.h>

#define NB 64
#define SEQL 512
#define L 510
#define T 9
#define H 768
#define EMS 12           // em row stride (floats)
#define WST 388          // s_emb window stride (32*12+4): +4 breaks 32-row bank aliasing
#define LN2 0.6931471805599453f

__device__ __forceinline__ float rl(float v, int l) {
  return __uint_as_float(__builtin_amdgcn_readlane(__float_as_uint(v), l));
}

// ---------------- K1: emissions = hidden[:,1:-1,:] @ W^T + bias --------------
// 1020 blocks x 256. Wave = 8 rows as 4 pairs, next pair always prefetched.
__global__ __launch_bounds__(256) void emis_kernel(
    const float* __restrict__ hidden, const float* __restrict__ weight,
    const float* __restrict__ bias, float* __restrict__ em,
    float* __restrict__ out) {
  __shared__ float4 wl[1728];  // 9x768 floats = 27.6 KB
  const float4* w4 = (const float4*)weight;
  for (int k = threadIdx.x; k < 1728; k += 256) wl[k] = w4[k];
  if (blockIdx.x == 0 && threadIdx.x == 0) out[0] = 0.f;  // atomic target init
  __syncthreads();
  const int lane = threadIdx.x & 63;
  const int wv = threadIdx.x >> 6;
  const int base = blockIdx.x * 32 + wv * 8;
  const float bj = bias[lane < 9 ? lane : 0];

  float4 ha[3], hb[3];
  {
    const int r0 = base, r1 = base + 1;
    const int b0 = r0 / L, p0 = r0 - b0 * L;
    const int b1 = r1 / L, p1 = r1 - b1 * L;
    const float4* h0 = (const float4*)(hidden + ((size_t)(b0 * SEQL + p0 + 1)) * H);
    const float4* h1 = (const float4*)(hidden + ((size_t)(b1 * SEQL + p1 + 1)) * H);
#pragma unroll
    for (int k = 0; k < 3; ++k) { ha[k] = h0[lane + 64 * k]; hb[k] = h1[lane + 64 * k]; }
  }
#pragma unroll 1
  for (int pr = 0; pr < 4; ++pr) {
    const int r0 = base + pr * 2, r1 = r0 + 1;
    float4 na[3], nb[3];
    if (pr < 3) {  // prefetch next pair first — overlaps the FMA block below
      const int q0 = r0 + 2, q1 = r0 + 3;
      const int c0 = q0 / L, s0 = q0 - c0 * L;
      const int c1 = q1 / L, s1 = q1 - c1 * L;
      const float4* h0 = (const float4*)(hidden + ((size_t)(c0 * SEQL + s0 + 1)) * H);
      const float4* h1 = (const float4*)(hidden + ((size_t)(c1 * SEQL + s1 + 1)) * H);
#pragma unroll
      for (int k = 0; k < 3; ++k) { na[k] = h0[lane + 64 * k]; nb[k] = h1[lane + 64 * k]; }
    }
    float a0[T], a1[T];
#pragma unroll
    for (int t = 0; t < T; ++t) { a0[t] = 0.f; a1[t] = 0.f; }
#pragma unroll
    for (int t = 0; t < T; ++t) {
#pragma unroll
      for (int k = 0; k < 3; ++k) {
        float4 w = wl[t * 192 + lane + 64 * k];
        a0[t] = fmaf(ha[k].x, w.x, fmaf(ha[k].y, w.y, fmaf(ha[k].z, w.z, fmaf(ha[k].w, w.w, a0[t]))));
        a1[t] = fmaf(hb[k].x, w.x, fmaf(hb[k].y, w.y, fmaf(hb[k].z, w.z, fmaf(hb[k].w, w.w, a1[t]))));
      }
    }
#pragma unroll
    for (int off = 32; off; off >>= 1) {
#pragma unroll
      for (int t = 0; t < T; ++t) {
        a0[t] += __shfl_xor(a0[t], off);
        a1[t] += __shfl_xor(a1[t], off);
      }
    }
    // lane t stores tag t: select acc[lane] via cndmask chain, one wide store/row
    float v0 = a0[0], v1 = a1[0];
#pragma unroll
    for (int t = 1; t < T; ++t) {
      v0 = (lane == t) ? a0[t] : v0;
      v1 = (lane == t) ? a1[t] : v1;
    }
    if (lane < 9) {
      em[(size_t)r0 * EMS + lane] = v0 + bj;
      em[(size_t)r1 * EMS + lane] = v1 + bj;
    }
#pragma unroll
    for (int k = 0; k < 3; ++k) { ha[k] = na[k]; hb[k] = nb[k]; }
  }
}

// ---------------- K2: per-batch CRF, fully LDS-local -------------------------
// 64 blocks x 256. Stage em(batch) -> LDS; 32 window scans (2 rounds x 4 waves
// x 4 nine-lane groups); compose + chase + path re-run (R5 numerics, absmax 0).
__global__ __launch_bounds__(256) void kb_kernel(
    const float* __restrict__ em, const int* __restrict__ labels,
    const float* __restrict__ start_t, const float* __restrict__ end_t,
    const float* __restrict__ trans, float* __restrict__ out) {
  __shared__ float s_emb[16 * WST];       // 24832 B
  __shared__ float s_pd[1296];
  __shared__ float s_mv[1296];
  __shared__ float s_A[153];
  __shared__ float s_t[81];
  __shared__ float s_np[4];
  __shared__ int s_lab[L];
  __shared__ unsigned char s_ch[32];
  __shared__ uint32_t s_bp[32 * 16 * 2];  // 4 KB
  const int b = blockIdx.x;
  const int tid = threadIdx.x;

  for (int k = tid; k < 81; k += 256) s_t[k] = trans[k];
  for (int k = tid; k < L; k += 256) s_lab[k] = labels[b * SEQL + 1 + k];
  // stage em rows 1..509 as [window][row][12] (float4 moves)
  for (int idx = tid; idx < 16 * 32 * 3; idx += 256) {
    const int s = idx / 96, rem = idx - 96 * s;
    const int r = rem / 3, c = rem - 3 * r;
    const int row = 32 * s + 1 + r;
    if (row < L) {
      float4 v = *(const float4*)(em + ((size_t)(b * L + row)) * EMS + c * 4);
      *(float4*)(s_emb + s * WST + r * 12 + c * 4) = v;
    }
  }
  __syncthreads();

  // ---- numerator (mask all-true) ----
  float part = 0.f;
  for (int l = tid; l < L; l += 256) {
    int tg = s_lab[l];
    float e = em[((size_t)(b * L + l)) * EMS + tg];
    if (l == 0) part += start_t[tg] + e;
    else part += s_t[s_lab[l - 1] * 9 + tg] + e;
    if (l == L - 1) part += end_t[tg];
  }
#pragma unroll
  for (int off = 32; off; off >>= 1) part += __shfl_xor(part, off);
  if ((tid & 63) == 0) s_np[tid >> 6] = part;

  // ---- window scans: lane = group g (0..6) x row i9; groups 0..3 active ----
  const int lane = tid & 63, wv = tid >> 6;
  const int g = lane / 9;
  const int i9 = lane - g * 9;
  const bool act = g < 4;
  const int sw = wv * 4 + (act ? g : 0);
  const int ntw = (sw == 15) ? 29 : 32;
  const float* ew = s_emb + sw * WST;

  {  // round 0: denominator transfer matrix (linear domain, pow2 rescale)
    float E[81];
#pragma unroll
    for (int k = 0; k < 81; ++k) E[k] = __expf(trans[k]);
    float R[9];
#pragma unroll
    for (int j = 0; j < 9; ++j) R[j] = E[i9 * 9 + j] * __expf(ew[j]);
    int iexp = 0;
    for (int t = 1; t < ntw; ++t) {
      float e[9];
#pragma unroll
      for (int j = 0; j < 9; ++j) e[j] = __expf(ew[t * 12 + j]);
      float Rn[9];
#pragma unroll
      for (int j = 0; j < 9; ++j) {
        float a = R[0] * E[0 * 9 + j];
#pragma unroll
        for (int k = 1; k < 9; ++k) a = fmaf(R[k], E[k * 9 + j], a);
        Rn[j] = a;
      }
#pragma unroll
      for (int j = 0; j < 9; ++j) R[j] = Rn[j] * e[j];
      if ((t & 3) == 0) {
        float mx = R[0];
#pragma unroll
        for (int j = 1; j < 9; ++j) mx = fmaxf(mx, R[j]);
        int ex = (int)((__float_as_uint(mx) >> 23) & 0xff) - 127;
        iexp += ex;
        float sc = __uint_as_float((uint32_t)(127 - ex) << 23);
#pragma unroll
        for (int j = 0; j < 9; ++j) R[j] *= sc;
      }
    }
    if (act) {
      float ls = (float)iexp * LN2;
#pragma unroll
      for (int j = 0; j < 9; ++j)
        s_pd[sw * 81 + j * 9 + i9] = __logf(R[j]) + ls;
    }
  }
  {  // round 1: viterbi max-plus transfer matrix
    float V[9];
#pragma unroll
    for (int j = 0; j < 9; ++j) V[j] = trans[i9 * 9 + j] + ew[j];
    for (int t = 1; t < ntw; ++t) {
      float Vn[9];
#pragma unroll
      for (int j = 0; j < 9; ++j) {
        float m = V[0] + trans[0 * 9 + j];
#pragma unroll
        for (int k = 1; k < 9; ++k) m = fmaxf(m, V[k] + trans[k * 9 + j]);
        Vn[j] = m + ew[t * 12 + j];
      }
#pragma unroll
      for (int j = 0; j < 9; ++j) V[j] = Vn[j];
    }
    if (act) {
#pragma unroll
      for (int j = 0; j < 9; ++j) s_mv[sw * 81 + j * 9 + i9] = V[j];
    }
  }
  __syncthreads();

  // ---- compose + chase (wave 0) ----
  if (tid < 64) {
    const int jj = lane < 9 ? lane : 8;
    float D = start_t[jj] + em[(size_t)b * L * EMS + jj];
    for (int s = 0; s < 16; ++s) {
      const float* col = &s_pd[s * 81 + jj * 9];
      float v0 = rl(D, 0) + col[0], v1 = rl(D, 1) + col[1], v2 = rl(D, 2) + col[2];
      float v3 = rl(D, 3) + col[3], v4 = rl(D, 4) + col[4], v5 = rl(D, 5) + col[5];
      float v6 = rl(D, 6) + col[6], v7 = rl(D, 7) + col[7], v8 = rl(D, 8) + col[8];
      float mx = fmaxf(fmaxf(fmaxf(fmaxf(v0, v1), fmaxf(v2, v3)),
                             fmaxf(fmaxf(v4, v5), fmaxf(v6, v7))), v8);
      float sum = __expf(v0 - mx) + __expf(v1 - mx) + __expf(v2 - mx) +
                  __expf(v3 - mx) + __expf(v4 - mx) + __expf(v5 - mx) +
                  __expf(v6 - mx) + __expf(v7 - mx) + __expf(v8 - mx);
      D = mx + __logf(sum);
    }
    float fe = D + end_t[jj];
    float w0 = rl(fe, 0), w1 = rl(fe, 1), w2 = rl(fe, 2), w3 = rl(fe, 3);
    float w4 = rl(fe, 4), w5 = rl(fe, 5), w6 = rl(fe, 6), w7 = rl(fe, 7), w8 = rl(fe, 8);
    float mx = fmaxf(fmaxf(fmaxf(fmaxf(w0, w1), fmaxf(w2, w3)),
                           fmaxf(fmaxf(w4, w5), fmaxf(w6, w7))), w8);
    float den = mx + __logf(__expf(w0 - mx) + __expf(w1 - mx) + __expf(w2 - mx) +
                            __expf(w3 - mx) + __expf(w4 - mx) + __expf(w5 - mx) +
                            __expf(w6 - mx) + __expf(w7 - mx) + __expf(w8 - mx));
    if (lane == 0)
      atomicAdd(out, den - (s_np[0] + s_np[1] + s_np[2] + s_np[3]));

    float A = start_t[jj] + em[(size_t)b * L * EMS + jj];
    if (lane < 9) s_A[lane] = A;
    for (int s = 0; s < 16; ++s) {
      const float* col = &s_mv[s * 81 + jj * 9];
      float u0 = rl(A, 0) + col[0], u1 = rl(A, 1) + col[1], u2 = rl(A, 2) + col[2];
      float u3 = rl(A, 3) + col[3], u4 = rl(A, 4) + col[4], u5 = rl(A, 5) + col[5];
      float u6 = rl(A, 6) + col[6], u7 = rl(A, 7) + col[7], u8 = rl(A, 8) + col[8];
      A = fmaxf(fmaxf(fmaxf(fmaxf(u0, u1), fmaxf(u2, u3)),
                      fmaxf(fmaxf(u4, u5), fmaxf(u6, u7))), u8);
      if (lane < 9) s_A[(s + 1) * 9 + lane] = A;
    }
    float fv = A + end_t[jj];
    int j = 0;
    {
      float bv = rl(fv, 0);
#pragma unroll
      for (int i = 1; i < 9; ++i) { float v = rl(fv, i); if (v > bv) { bv = v; j = i; } }
    }
    for (int s = 15; s >= 0; --s) {
      float val = s_A[s * 9 + jj] + s_mv[s * 81 + j * 9 + jj];
      int ii = 0;
      float bb = rl(val, 0);
#pragma unroll
      for (int i = 1; i < 9; ++i) { float v = rl(val, i); if (v > bb) { bb = v; ii = i; } }
      if (lane == 0) {
        s_ch[s * 2] = (unsigned char)ii;
        s_ch[s * 2 + 1] = (unsigned char)j;
      }
      j = ii;
    }
    if (lane == 0) out[1 + (size_t)b * L] = (float)j;  // tag at position 0
  }
  __syncthreads();

  // ---- path re-run: thread s = window s, emissions from LDS ----
  if (tid < 16) {
    const int s = tid;
    const int nt = (s == 15) ? 29 : 32;
    const int l0 = 32 * s + 1;
    const int i0 = s_ch[s * 2];
    const int jF = s_ch[s * 2 + 1];
    const float* ep = s_emb + s * WST;
    float a[9];
#pragma unroll
    for (int jx = 0; jx < 9; ++jx) a[jx] = trans[i0 * 9 + jx] + ep[jx];
    for (int q = 1; q < nt; ++q) {
      uint32_t pk0 = 0, pk1 = 0;
      float an[9];
#pragma unroll
      for (int jx = 0; jx < 9; ++jx) {
        float best = a[0] + trans[0 * 9 + jx];
        int bi = 0;
#pragma unroll
        for (int k = 1; k < 9; ++k) {
          float v = a[k] + trans[k * 9 + jx];
          if (v > best) { best = v; bi = k; }
        }
        an[jx] = best + ep[q * 12 + jx];
        if (jx < 8) pk0 |= ((uint32_t)bi) << (4 * jx);
        else pk1 = (uint32_t)bi;
      }
      s_bp[(q * 16 + s) * 2] = pk0;
      s_bp[(q * 16 + s) * 2 + 1] = pk1;
#pragma unroll
      for (int jx = 0; jx < 9; ++jx) a[jx] = an[jx];
    }
    int cur = jF;
    float* orow = out + 1 + (size_t)b * L + l0;
    for (int q = nt - 1; q >= 1; --q) {
      orow[q] = (float)cur;
      uint32_t pk = s_bp[(q * 16 + s) * 2 + (cur >> 3)];
      cur = (int)((pk >> ((cur & 7) * 4)) & 15u);
    }
    orow[0] = (float)cur;
  }
}

extern "C" void kernel_launch(void* const* d_in, const int* in_sizes, int n_in,
                              void* d_out, int out_size, void* d_ws, size_t ws_size,
                              hipStream_t stream) {
  const float* hidden  = (const float*)d_in[0];
  const int*   labels  = (const int*)d_in[1];
  const float* weight  = (const float*)d_in[2];
  const float* bias    = (const float*)d_in[3];
  const float* start_t = (const float*)d_in[4];
  const float* end_t   = (const float*)d_in[5];
  const float* trans   = (const float*)d_in[6];
  float* out = (float*)d_out;

  float* em = (float*)d_ws;  // 64*510*12 floats = 1.57 MB

  emis_kernel<<<1020, 256, 0, stream>>>(hidden, weight, bias, em, out);
  kb_kernel<<<NB, 256, 0, stream>>>(em, labels, start_t, end_t, trans, out);
}

// Round 7
// 229.235 us; speedup vs baseline: 1.0823x; 1.0189x over previous
//
#include <hip/hip_runtime.h>
#include <stdint.h>

#define NB 64
#define SEQL 512
#define L 510
#define T 9
#define H 768
#define EMS 12           // em row stride (floats)
#define WST 388          // s_emb window stride (32*12+4): +4 breaks 32-row bank aliasing
#define LN2 0.6931471805599453f

__device__ __forceinline__ float rl(float v, int l) {
  return __uint_as_float(__builtin_amdgcn_readlane(__float_as_uint(v), l));
}

// ---------------- K1: emissions = hidden[:,1:-1,:] @ W^T + bias --------------
// 1020 blocks x 256. Wave = 8 rows as 4 pairs, next pair always prefetched.
// (unchanged from R6 — absmax 0; counters not yet seen for this kernel)
__global__ __launch_bounds__(256) void emis_kernel(
    const float* __restrict__ hidden, const float* __restrict__ weight,
    const float* __restrict__ bias, float* __restrict__ em,
    float* __restrict__ out) {
  __shared__ float4 wl[1728];  // 9x768 floats = 27.6 KB
  const float4* w4 = (const float4*)weight;
  for (int k = threadIdx.x; k < 1728; k += 256) wl[k] = w4[k];
  if (blockIdx.x == 0 && threadIdx.x == 0) out[0] = 0.f;  // atomic target init
  __syncthreads();
  const int lane = threadIdx.x & 63;
  const int wv = threadIdx.x >> 6;
  const int base = blockIdx.x * 32 + wv * 8;
  const float bj = bias[lane < 9 ? lane : 0];

  float4 ha[3], hb[3];
  {
    const int r0 = base, r1 = base + 1;
    const int b0 = r0 / L, p0 = r0 - b0 * L;
    const int b1 = r1 / L, p1 = r1 - b1 * L;
    const float4* h0 = (const float4*)(hidden + ((size_t)(b0 * SEQL + p0 + 1)) * H);
    const float4* h1 = (const float4*)(hidden + ((size_t)(b1 * SEQL + p1 + 1)) * H);
#pragma unroll
    for (int k = 0; k < 3; ++k) { ha[k] = h0[lane + 64 * k]; hb[k] = h1[lane + 64 * k]; }
  }
#pragma unroll 1
  for (int pr = 0; pr < 4; ++pr) {
    const int r0 = base + pr * 2, r1 = r0 + 1;
    float4 na[3], nb[3];
    if (pr < 3) {  // prefetch next pair first — overlaps the FMA block below
      const int q0 = r0 + 2, q1 = r0 + 3;
      const int c0 = q0 / L, s0 = q0 - c0 * L;
      const int c1 = q1 / L, s1 = q1 - c1 * L;
      const float4* h0 = (const float4*)(hidden + ((size_t)(c0 * SEQL + s0 + 1)) * H);
      const float4* h1 = (const float4*)(hidden + ((size_t)(c1 * SEQL + s1 + 1)) * H);
#pragma unroll
      for (int k = 0; k < 3; ++k) { na[k] = h0[lane + 64 * k]; nb[k] = h1[lane + 64 * k]; }
    }
    float a0[T], a1[T];
#pragma unroll
    for (int t = 0; t < T; ++t) { a0[t] = 0.f; a1[t] = 0.f; }
#pragma unroll
    for (int t = 0; t < T; ++t) {
#pragma unroll
      for (int k = 0; k < 3; ++k) {
        float4 w = wl[t * 192 + lane + 64 * k];
        a0[t] = fmaf(ha[k].x, w.x, fmaf(ha[k].y, w.y, fmaf(ha[k].z, w.z, fmaf(ha[k].w, w.w, a0[t]))));
        a1[t] = fmaf(hb[k].x, w.x, fmaf(hb[k].y, w.y, fmaf(hb[k].z, w.z, fmaf(hb[k].w, w.w, a1[t]))));
      }
    }
#pragma unroll
    for (int off = 32; off; off >>= 1) {
#pragma unroll
      for (int t = 0; t < T; ++t) {
        a0[t] += __shfl_xor(a0[t], off);
        a1[t] += __shfl_xor(a1[t], off);
      }
    }
    float v0 = a0[0], v1 = a1[0];
#pragma unroll
    for (int t = 1; t < T; ++t) {
      v0 = (lane == t) ? a0[t] : v0;
      v1 = (lane == t) ? a1[t] : v1;
    }
    if (lane < 9) {
      em[(size_t)r0 * EMS + lane] = v0 + bj;
      em[(size_t)r1 * EMS + lane] = v1 + bj;
    }
#pragma unroll
    for (int k = 0; k < 3; ++k) { ha[k] = na[k]; hb[k] = nb[k]; }
  }
}

// ---------------- K2: per-batch CRF, fully LDS-local, 512 threads ------------
// waves 0-3: den scans (16 windows). waves 4-7: viterbi scans (16 windows),
// concurrent. Identity-start transfer matrices: NO dynamic register-array
// indexing anywhere (that was the R6 scratch-spill bottleneck).
__global__ __launch_bounds__(512, 2) void kb_kernel(
    const float* __restrict__ em, const int* __restrict__ labels,
    const float* __restrict__ start_t, const float* __restrict__ end_t,
    const float* __restrict__ trans, float* __restrict__ out) {
  __shared__ float s_emb[16 * WST];       // 24832 B
  __shared__ float s_pd[1296];
  __shared__ float s_mv[1296];
  __shared__ float s_A[153];
  __shared__ float s_t[81];
  __shared__ float s_np[8];
  __shared__ int s_lab[L];
  __shared__ unsigned char s_ch[32];
  __shared__ uint32_t s_bp[32 * 16 * 2];  // 4 KB
  const int b = blockIdx.x;
  const int tid = threadIdx.x;

  for (int k = tid; k < 81; k += 512) s_t[k] = trans[k];
  for (int k = tid; k < L; k += 512) s_lab[k] = labels[b * SEQL + 1 + k];
  // stage em rows 1..509 as [window][row][12] (float4 moves)
  for (int idx = tid; idx < 16 * 32 * 3; idx += 512) {
    const int s = idx / 96, rem = idx - 96 * s;
    const int r = rem / 3, c = rem - 3 * r;
    const int row = 32 * s + 1 + r;
    if (row < L) {
      float4 v = *(const float4*)(em + ((size_t)(b * L + row)) * EMS + c * 4);
      *(float4*)(s_emb + s * WST + r * 12 + c * 4) = v;
    }
  }
  __syncthreads();

  // ---- numerator (mask all-true), emissions from LDS ----
  float part = 0.f;
  for (int l = tid; l < L; l += 512) {
    int tg = s_lab[l];
    float e;
    if (l == 0) e = em[(size_t)b * L * EMS + tg];           // row 0 not staged
    else {
      int s = (l - 1) >> 5, r = (l - 1) & 31;
      e = s_emb[s * WST + r * 12 + tg];
    }
    if (l == 0) part += start_t[tg] + e;
    else part += s_t[s_lab[l - 1] * 9 + tg] + e;
    if (l == L - 1) part += end_t[tg];
  }
#pragma unroll
  for (int off = 32; off; off >>= 1) part += __shfl_xor(part, off);
  if ((tid & 63) == 0) s_np[tid >> 6] = part;

  // ---- window scans ----
  const int lane = tid & 63;
  const int wvq = tid >> 6;          // 0..7
  const int g = lane / 9;
  const int i9 = lane - g * 9;
  const bool act = g < 4;
  const int sw = (wvq & 3) * 4 + (act ? g : 0);
  const int ntw = (sw == 15) ? 29 : 32;
  const float* ew = s_emb + sw * WST;

  if (wvq < 4) {
    // ===== den: linear-domain transfer matrix, identity start ==============
    float E[81];
#pragma unroll
    for (int k = 0; k < 81; ++k) E[k] = __expf(trans[k]);   // constant idx only
    float R[9];
#pragma unroll
    for (int j = 0; j < 9; ++j) R[j] = (i9 == j) ? 1.f : 0.f;
    int iexp = 0;
    for (int u = 0; u < ntw; ++u) {
      float e[9];
#pragma unroll
      for (int j = 0; j < 9; ++j) e[j] = __expf(ew[u * 12 + j]);
      float Rn[9];
#pragma unroll
      for (int j = 0; j < 9; ++j) {
        float a = R[0] * E[j];
#pragma unroll
        for (int k = 1; k < 9; ++k) a = fmaf(R[k], E[k * 9 + j], a);
        Rn[j] = a * e[j];
      }
#pragma unroll
      for (int j = 0; j < 9; ++j) R[j] = Rn[j];
      if (u && (u & 3) == 0) {  // power-of-2 rescale (same cadence as R6)
        float mx = R[0];
#pragma unroll
        for (int j = 1; j < 9; ++j) mx = fmaxf(mx, R[j]);
        int ex = (int)((__float_as_uint(mx) >> 23) & 0xff) - 127;
        iexp += ex;
        float sc = __uint_as_float((uint32_t)(127 - ex) << 23);
#pragma unroll
        for (int j = 0; j < 9; ++j) R[j] *= sc;
      }
    }
    if (act) {
      float ls = (float)iexp * LN2;
#pragma unroll
      for (int j = 0; j < 9; ++j)
        s_pd[sw * 81 + j * 9 + i9] = __logf(R[j]) + ls;
    }
  } else {
    // ===== viterbi: max-plus transfer matrix, identity start ===============
    float tr[81];
#pragma unroll
    for (int k = 0; k < 81; ++k) tr[k] = trans[k];          // constant idx only
    float V[9];
#pragma unroll
    for (int j = 0; j < 9; ++j) V[j] = (i9 == j) ? 0.f : -1e30f;
    for (int u = 0; u < ntw; ++u) {
      float Vn[9];
#pragma unroll
      for (int j = 0; j < 9; ++j) {
        float m = V[0] + tr[j];
#pragma unroll
        for (int k = 1; k < 9; ++k) m = fmaxf(m, V[k] + tr[k * 9 + j]);
        Vn[j] = m + ew[u * 12 + j];
      }
#pragma unroll
      for (int j = 0; j < 9; ++j) V[j] = Vn[j];
    }
    if (act) {
#pragma unroll
      for (int j = 0; j < 9; ++j) s_mv[sw * 81 + j * 9 + i9] = V[j];
    }
  }
  __syncthreads();

  // ---- compose + chase (wave 0) — verbatim R6 numerics (absmax 0) ----
  if (tid < 64) {
    const int jj = lane < 9 ? lane : 8;
    float D = start_t[jj] + em[(size_t)b * L * EMS + jj];
    for (int s = 0; s < 16; ++s) {
      const float* col = &s_pd[s * 81 + jj * 9];
      float v0 = rl(D, 0) + col[0], v1 = rl(D, 1) + col[1], v2 = rl(D, 2) + col[2];
      float v3 = rl(D, 3) + col[3], v4 = rl(D, 4) + col[4], v5 = rl(D, 5) + col[5];
      float v6 = rl(D, 6) + col[6], v7 = rl(D, 7) + col[7], v8 = rl(D, 8) + col[8];
      float mx = fmaxf(fmaxf(fmaxf(fmaxf(v0, v1), fmaxf(v2, v3)),
                             fmaxf(fmaxf(v4, v5), fmaxf(v6, v7))), v8);
      float sum = __expf(v0 - mx) + __expf(v1 - mx) + __expf(v2 - mx) +
                  __expf(v3 - mx) + __expf(v4 - mx) + __expf(v5 - mx) +
                  __expf(v6 - mx) + __expf(v7 - mx) + __expf(v8 - mx);
      D = mx + __logf(sum);
    }
    float fe = D + end_t[jj];
    float w0 = rl(fe, 0), w1 = rl(fe, 1), w2 = rl(fe, 2), w3 = rl(fe, 3);
    float w4 = rl(fe, 4), w5 = rl(fe, 5), w6 = rl(fe, 6), w7 = rl(fe, 7), w8 = rl(fe, 8);
    float mx = fmaxf(fmaxf(fmaxf(fmaxf(w0, w1), fmaxf(w2, w3)),
                           fmaxf(fmaxf(w4, w5), fmaxf(w6, w7))), w8);
    float den = mx + __logf(__expf(w0 - mx) + __expf(w1 - mx) + __expf(w2 - mx) +
                            __expf(w3 - mx) + __expf(w4 - mx) + __expf(w5 - mx) +
                            __expf(w6 - mx) + __expf(w7 - mx) + __expf(w8 - mx));
    if (lane == 0)
      atomicAdd(out, den - (s_np[0] + s_np[1] + s_np[2] + s_np[3] +
                            s_np[4] + s_np[5] + s_np[6] + s_np[7]));

    float A = start_t[jj] + em[(size_t)b * L * EMS + jj];
    if (lane < 9) s_A[lane] = A;
    for (int s = 0; s < 16; ++s) {
      const float* col = &s_mv[s * 81 + jj * 9];
      float u0 = rl(A, 0) + col[0], u1 = rl(A, 1) + col[1], u2 = rl(A, 2) + col[2];
      float u3 = rl(A, 3) + col[3], u4 = rl(A, 4) + col[4], u5 = rl(A, 5) + col[5];
      float u6 = rl(A, 6) + col[6], u7 = rl(A, 7) + col[7], u8 = rl(A, 8) + col[8];
      A = fmaxf(fmaxf(fmaxf(fmaxf(u0, u1), fmaxf(u2, u3)),
                      fmaxf(fmaxf(u4, u5), fmaxf(u6, u7))), u8);
      if (lane < 9) s_A[(s + 1) * 9 + lane] = A;
    }
    float fv = A + end_t[jj];
    int j = 0;
    {
      float bv = rl(fv, 0);
#pragma unroll
      for (int i = 1; i < 9; ++i) { float v = rl(fv, i); if (v > bv) { bv = v; j = i; } }
    }
    for (int s = 15; s >= 0; --s) {
      float val = s_A[s * 9 + jj] + s_mv[s * 81 + j * 9 + jj];
      int ii = 0;
      float bb = rl(val, 0);
#pragma unroll
      for (int i = 1; i < 9; ++i) { float v = rl(val, i); if (v > bb) { bb = v; ii = i; } }
      if (lane == 0) {
        s_ch[s * 2] = (unsigned char)ii;
        s_ch[s * 2 + 1] = (unsigned char)j;
      }
      j = ii;
    }
    if (lane == 0) out[1 + (size_t)b * L] = (float)j;  // tag at position 0
  }
  __syncthreads();

  // ---- path re-run: thread s = window s, emissions from LDS (R6 verbatim) ----
  if (tid < 16) {
    const int s = tid;
    const int nt = (s == 15) ? 29 : 32;
    const int l0 = 32 * s + 1;
    const int i0 = s_ch[s * 2];
    const int jF = s_ch[s * 2 + 1];
    const float* ep = s_emb + s * WST;
    float a[9];
#pragma unroll
    for (int jx = 0; jx < 9; ++jx) a[jx] = trans[i0 * 9 + jx] + ep[jx];
    for (int q = 1; q < nt; ++q) {
      uint32_t pk0 = 0, pk1 = 0;
      float an[9];
#pragma unroll
      for (int jx = 0; jx < 9; ++jx) {
        float best = a[0] + trans[0 * 9 + jx];
        int bi = 0;
#pragma unroll
        for (int k = 1; k < 9; ++k) {
          float v = a[k] + trans[k * 9 + jx];
          if (v > best) { best = v; bi = k; }
        }
        an[jx] = best + ep[q * 12 + jx];
        if (jx < 8) pk0 |= ((uint32_t)bi) << (4 * jx);
        else pk1 = (uint32_t)bi;
      }
      s_bp[(q * 16 + s) * 2] = pk0;
      s_bp[(q * 16 + s) * 2 + 1] = pk1;
#pragma unroll
      for (int jx = 0; jx < 9; ++jx) a[jx] = an[jx];
    }
    int cur = jF;
    float* orow = out + 1 + (size_t)b * L + l0;
    for (int q = nt - 1; q >= 1; --q) {
      orow[q] = (float)cur;
      uint32_t pk = s_bp[(q * 16 + s) * 2 + (cur >> 3)];
      cur = (int)((pk >> ((cur & 7) * 4)) & 15u);
    }
    orow[0] = (float)cur;
  }
}

extern "C" void kernel_launch(void* const* d_in, const int* in_sizes, int n_in,
                              void* d_out, int out_size, void* d_ws, size_t ws_size,
                              hipStream_t stream) {
  const float* hidden  = (const float*)d_in[0];
  const int*   labels  = (const int*)d_in[1];
  const float* weight  = (const float*)d_in[2];
  const float* bias    = (const float*)d_in[3];
  const float* start_t = (const float*)d_in[4];
  const float* end_t   = (const float*)d_in[5];
  const float* trans   = (const float*)d_in[6];
  float* out = (float*)d_out;

  float* em = (float*)d_ws;  // 64*510*12 floats = 1.57 MB

  emis_kernel<<<1020, 256, 0, stream>>>(hidden, weight, bias, em, out);
  kb_kernel<<<NB, 512, 0, stream>>>(em, labels, start_t, end_t, trans, out);
}